// Round 6
// baseline (161.777 us; speedup 1.0000x reference)
//
#include <hip/hip_runtime.h>
#include <hip/hip_bf16.h>

#define B_ 2
#define T_ 2048
#define C_ 1024
#define H_ 16
#define D_ 64
#define M1 4096
#define N1 3072
#define K_ 1024

typedef __attribute__((ext_vector_type(8))) __bf16 bf16x8;
typedef __attribute__((ext_vector_type(4))) float f32x4;
typedef __attribute__((ext_vector_type(8))) unsigned short ushort8_t;
typedef __attribute__((ext_vector_type(4))) unsigned short ushort4_t;

static __device__ __forceinline__ unsigned short f2bf(float f) {
    unsigned int u = __builtin_bit_cast(unsigned int, f);
    u += 0x7fffu + ((u >> 16) & 1u);
    return (unsigned short)(u >> 16);
}
static __device__ __forceinline__ unsigned short f2bf_hw(float f) {
    return __builtin_bit_cast(unsigned short, (__bf16)f);
}
static __device__ __forceinline__ bf16x8 bload(const unsigned short* p) {
    return __builtin_bit_cast(bf16x8, *(const ushort8_t*)p);
}

// fast exp2 -> v_exp_f32
#if defined(__has_builtin)
#if __has_builtin(__builtin_amdgcn_exp2f)
#define HAVE_EXP2_BUILTIN 1
#endif
#endif
static __device__ __forceinline__ float fexp2(float x) {
#ifdef HAVE_EXP2_BUILTIN
    return __builtin_amdgcn_exp2f(x);
#else
    float r; asm("v_exp_f32 %0, %1" : "=v"(r) : "v"(x)); return r;
#endif
}

// ---- DPP 16-lane reductions (VALU-rate, no LDS pipe) ----
template <int CTRL>
static __device__ __forceinline__ float dpp_mov(float v) {
    return __builtin_bit_cast(float,
        __builtin_amdgcn_update_dpp(0, __builtin_bit_cast(int, v), CTRL, 0xF, 0xF, true));
}
static __device__ __forceinline__ float dpp_fmax16(float v) {
    v = fmaxf(v, dpp_mov<0xB1>(v));
    v = fmaxf(v, dpp_mov<0x4E>(v));
    v = fmaxf(v, dpp_mov<0x141>(v));
    v = fmaxf(v, dpp_mov<0x140>(v));
    return v;
}
static __device__ __forceinline__ float dpp_fadd16(float v) {
    v += dpp_mov<0xB1>(v);
    v += dpp_mov<0x4E>(v);
    v += dpp_mov<0x141>(v);
    v += dpp_mov<0x140>(v);
    return v;
}

// ---- async global->LDS (16B per lane; LDS dest wave-uniform base + lane*16) ----
typedef __attribute__((address_space(1))) const unsigned int gu32;
typedef __attribute__((address_space(3))) unsigned int lu32;
static __device__ __forceinline__ void gld16(const void* g, void* l) {
    __builtin_amdgcn_global_load_lds((gu32*)g, (lu32*)l, 16, 0, 0);
}

#define VMCNT(n) asm volatile("s_waitcnt vmcnt(" #n ")" ::: "memory")
#define LGKM0    asm volatile("s_waitcnt lgkmcnt(0)" ::: "memory")

// ---------------- cast x -> bf16 ----------------
__global__ void cast_x_kernel(const float* __restrict__ in,
                              unsigned short* __restrict__ out, int n4) {
    int idx = blockIdx.x * blockDim.x + threadIdx.x;
    int stride = gridDim.x * blockDim.x;
    for (int i = idx; i < n4; i += stride) {
        float4 v = ((const float4*)in)[i];
        ushort4_t o;
        o.x = f2bf(v.x); o.y = f2bf(v.y); o.z = f2bf(v.z); o.w = f2bf(v.w);
        ((ushort4_t*)out)[i] = o;
    }
}

// ------------- transpose f32[K][N] -> bf16[N][K] -------------
__global__ void transpose_cast_kernel(const float* __restrict__ in,
                                      unsigned short* __restrict__ out,
                                      int K, int N) {
    __shared__ float tile[32][33];
    int tx = threadIdx.x & 31;
    int ty = threadIdx.x >> 5;
    int n0 = blockIdx.x * 32;
    int k0 = blockIdx.y * 32;
#pragma unroll
    for (int rr = 0; rr < 32; rr += 8)
        tile[ty + rr][tx] = in[(size_t)(k0 + ty + rr) * N + n0 + tx];
    __syncthreads();
#pragma unroll
    for (int rr = 0; rr < 32; rr += 8)
        out[(size_t)(n0 + ty + rr) * K + k0 + tx] = f2bf(tile[tx][ty + rr]);
}

// =================== GEMM common body (dbuf LDS via global_load_lds) ===================

#define GEMM_PROLOGUE()                                                                  \
    __shared__ unsigned short As[2][128 * 32];                                           \
    __shared__ unsigned short Bs[2][128 * 32];                                           \
    const int tid = threadIdx.x;                                                         \
    const int lane = tid & 63;                                                           \
    const int wave = tid >> 6;                                                           \
    const int g = lane >> 4, cl = lane & 15;                                             \
    const int wr = (wave >> 1) * 64, wc = (wave & 1) * 64;                               \
    const int row0 = blockIdx.x * 128;                                                   \
    const int col0 = blockIdx.y * 128;                                                   \
    const int srow = tid >> 2;  /* 0..63 */                                              \
    const int sgran = tid & 3;                                                           \
    f32x4 acc[4][4];                                                                     \
    _Pragma("unroll") for (int m = 0; m < 4; ++m)                                        \
        _Pragma("unroll") for (int n = 0; n < 4; ++n)                                    \
            acc[m][n] = (f32x4){0.f, 0.f, 0.f, 0.f};                                     \
    auto stage = [&](int buf, int k0) {                                                  \
        _Pragma("unroll") for (int c = 0; c < 2; ++c) {                                  \
            int r = srow + c * 64;                                                       \
            gld16(A + (size_t)(row0 + r) * K_ + k0 + sgran * 8,                          \
                  (char*)&As[buf][0] + c * 4096 + wave * 1024);                          \
            gld16(Bt + (size_t)(col0 + r) * K_ + k0 + sgran * 8,                         \
                  (char*)&Bs[buf][0] + c * 4096 + wave * 1024);                          \
        }                                                                                \
    };                                                                                   \
    stage(0, 0);                                                                         \
    int buf = 0;                                                                         \
    for (int k0 = 0; k0 < K_; k0 += 32) {                                                \
        if (k0 + 32 < K_) { stage(buf ^ 1, k0 + 32); VMCNT(4); }                         \
        else              { VMCNT(0); }                                                  \
        __builtin_amdgcn_s_barrier();                                                    \
        bf16x8 af[4], bfv[4];                                                            \
        _Pragma("unroll") for (int m = 0; m < 4; ++m)                                    \
            af[m] = bload(&As[buf][(wr + m * 16 + cl) * 32 + g * 8]);                    \
        _Pragma("unroll") for (int n = 0; n < 4; ++n)                                    \
            bfv[n] = bload(&Bs[buf][(wc + n * 16 + cl) * 32 + g * 8]);                   \
        _Pragma("unroll") for (int m = 0; m < 4; ++m)                                    \
            _Pragma("unroll") for (int n = 0; n < 4; ++n)                                \
                acc[m][n] = __builtin_amdgcn_mfma_f32_16x16x32_bf16(                     \
                    af[m], bfv[n], acc[m][n], 0, 0, 0);                                  \
        LGKM0;                                                                           \
        __builtin_amdgcn_s_barrier();                                                    \
        buf ^= 1;                                                                        \
    }

// ---------------- GEMM1: qkv = Xb @ Wt1^T + b ----------------
__global__ __launch_bounds__(256)
void gemm_qkv_kernel(const unsigned short* __restrict__ A,   // [4096][1024] bf16
                     const unsigned short* __restrict__ Bt,  // [3072][1024] bf16
                     const float* __restrict__ bias,         // [3072]
                     unsigned short* __restrict__ Qo,        // [BH][T][D] (pre-scaled)
                     unsigned short* __restrict__ Ko,        // [BH][T][D]
                     unsigned short* __restrict__ Vt)        // [BH][D][T]
{
    GEMM_PROLOGUE()

    const float QSCALE = 0.125f * 1.44269504088896340736f;  // 1/sqrt(D) * log2(e)
#pragma unroll
    for (int m = 0; m < 4; ++m) {
        int i0 = row0 + wr + m * 16 + g * 4;
#pragma unroll
        for (int n = 0; n < 4; ++n) {
            int j = col0 + wc + n * 16 + cl;
            int which = j >> 10;
            int c = j & 1023;
            int h = c >> 6, d = c & 63;
            float bv = bias[j];
#pragma unroll
            for (int r = 0; r < 4; ++r) {
                int i = i0 + r;
                int b = i >> 11, t = i & 2047;
                size_t bh = (size_t)(b * H_ + h);
                float val = acc[m][n][r] + bv;
                if (which == 0) {
                    Qo[(bh * T_ + t) * D_ + d] = f2bf(val * QSCALE);
                } else if (which == 1) {
                    Ko[(bh * T_ + t) * D_ + d] = f2bf(val);
                } else {
                    Vt[(bh * D_ + d) * T_ + t] = f2bf(val);
                }
            }
        }
    }
}

// ---------------- GEMM2: out = AO @ Wt2^T + b (fp32 out) ----------------
__global__ __launch_bounds__(256)
void gemm_proj_kernel(const unsigned short* __restrict__ A,   // [4096][1024] bf16
                      const unsigned short* __restrict__ Bt,  // [1024][1024] bf16
                      const float* __restrict__ bias,         // [1024]
                      float* __restrict__ out)                // [4096][1024] f32
{
    GEMM_PROLOGUE()

#pragma unroll
    for (int m = 0; m < 4; ++m) {
        int i0 = row0 + wr + m * 16 + g * 4;
#pragma unroll
        for (int n = 0; n < 4; ++n) {
            int j = col0 + wc + n * 16 + cl;
            float bv = bias[j];
#pragma unroll
            for (int r = 0; r < 4; ++r)
                out[(size_t)(i0 + r) * C_ + j] = acc[m][n][r] + bv;
        }
    }
}

// ---------------- flash attention (causal, pair-balanced, KVBLK=128) ----------------
// grid (16, 32): block p handles q-tiles p and 31-p sequentially; with 128-wide
// kt-steps every block does exactly ceil((p+1)/2)+ceil((32-p)/2) = 17 steps.
// K staged in LDS (dbuf, XOR-swizzled, global_load_lds, counted vmcnt).
// V^T read directly from global (L1/L2-resident), issued after QK so softmax
// hides the latency. Softmax once per 128 cols.
__global__ __launch_bounds__(256)
void attn_kernel(const unsigned short* __restrict__ Q,   // [BH][T][D], pre-scaled by log2(e)/8
                 const unsigned short* __restrict__ Kb,  // [BH][T][D]
                 const unsigned short* __restrict__ Vh_, // [BH][D][T]
                 unsigned short* __restrict__ AO)        // [B][T][C] bf16
{
    __shared__ unsigned short Klds[2][128 * 64];  // 32 KB (dbuf)
    __shared__ unsigned short Plds[4][16][136];   // per-wave P transpose, 17 KB
    const int pair = blockIdx.x;  // 0..15
    const int bh = blockIdx.y;    // 0..31
    const int b = bh >> 4, h = bh & 15;
    const int tid = threadIdx.x;
    const int lane = tid & 63;
    const int wave = tid >> 6;
    const int g = lane >> 4, cl = lane & 15;

    const unsigned short* Qh = Q + (size_t)bh * T_ * D_;
    const unsigned short* Kh = Kb + (size_t)bh * T_ * D_;
    const unsigned short* Vh = Vh_ + (size_t)bh * D_ * T_;

    const int srow = tid >> 3;  // 0..31
    const int sg   = tid & 7;

    // stage one 128x64 K tile (16 KB) into buf; granule pre-swizzled lg = sg ^ (r&7)
    auto stage = [&](int bufi, int s) {
        int kb = s * 128;
#pragma unroll
        for (int c = 0; c < 4; ++c) {
            int r = c * 32 + srow;
            int lg = sg ^ (r & 7);
            gld16(Kh + (size_t)(kb + r) * D_ + lg * 8,
                  (char*)&Klds[bufi][0] + c * 4096 + wave * 1024);
        }
    };

    for (int half = 0; half < 2; ++half) {
        const int qt = half ? (31 - pair) : pair;
        const int q0 = qt * 64 + wave * 16;
        const int nsteps = (qt + 2) >> 1;

        bf16x8 qf[2];
#pragma unroll
        for (int c2 = 0; c2 < 2; ++c2)
            qf[c2] = bload(Qh + (size_t)(q0 + cl) * D_ + c2 * 32 + g * 8);

        f32x4 oacc[4];
#pragma unroll
        for (int n = 0; n < 4; ++n) oacc[n] = (f32x4){0.f, 0.f, 0.f, 0.f};
        float mrow[4] = {-INFINITY, -INFINITY, -INFINITY, -INFINITY};
        float lrow[4] = {0.f, 0.f, 0.f, 0.f};

        stage(0, 0);
        int buf = 0;
        for (int s = 0; s < nsteps; ++s) {
            if (s + 1 < nsteps) { stage(buf ^ 1, s + 1); VMCNT(4); }
            else                { VMCNT(0); }
            __builtin_amdgcn_s_barrier();

            const int kb = s * 128;
            // ---- QK^T: 128 cols from swizzled Klds ----
            f32x4 sc[8];
#pragma unroll
            for (int nn = 0; nn < 8; ++nn) {
                sc[nn] = (f32x4){0.f, 0.f, 0.f, 0.f};
#pragma unroll
                for (int c2 = 0; c2 < 2; ++c2) {
                    int pg = (c2 * 4 + g) ^ (cl & 7);
                    bf16x8 kf = bload(&Klds[buf][(nn * 16 + cl) * 64 + pg * 8]);
                    sc[nn] = __builtin_amdgcn_mfma_f32_16x16x32_bf16(qf[c2], kf, sc[nn], 0, 0, 0);
                }
            }
            // ---- V^T fragments direct from global (latency hidden by softmax) ----
            bf16x8 vf[4][4];  // [k-slice 32][n]
#pragma unroll
            for (int kk = 0; kk < 4; ++kk)
#pragma unroll
                for (int n = 0; n < 4; ++n)
                    vf[kk][n] = bload(Vh + (size_t)(n * 16 + cl) * T_ + kb + kk * 32 + g * 8);
            // ---- causal mask (only possible in final step) ----
            if (s == nsteps - 1) {
#pragma unroll
                for (int nn = 0; nn < 8; ++nn) {
                    int tk = kb + nn * 16 + cl;
#pragma unroll
                    for (int r = 0; r < 4; ++r) {
                        int tq = q0 + g * 4 + r;
                        if (tk > tq) sc[nn][r] = -INFINITY;
                    }
                }
            }
            // ---- online softmax over 128 cols (exp2 domain) ----
            float p0[8][4];
#pragma unroll
            for (int r = 0; r < 4; ++r) {
                float vmax = sc[0][r];
#pragma unroll
                for (int nn = 1; nn < 8; ++nn) vmax = fmaxf(vmax, sc[nn][r]);
                vmax = dpp_fmax16(vmax);
                float mn = fmaxf(mrow[r], vmax);
                float alpha = fexp2(mrow[r] - mn);
                float ps = 0.f;
#pragma unroll
                for (int nn = 0; nn < 8; ++nn) { p0[nn][r] = fexp2(sc[nn][r] - mn); ps += p0[nn][r]; }
                ps = dpp_fadd16(ps);
                lrow[r] = lrow[r] * alpha + ps;
                mrow[r] = mn;
#pragma unroll
                for (int n = 0; n < 4; ++n) oacc[n][r] *= alpha;
            }
            // ---- P transpose via per-wave LDS ----
#pragma unroll
            for (int nn = 0; nn < 8; ++nn)
#pragma unroll
                for (int r = 0; r < 4; ++r)
                    Plds[wave][g * 4 + r][nn * 16 + cl] = f2bf_hw(p0[nn][r]);
            bf16x8 pf[4];
#pragma unroll
            for (int kk = 0; kk < 4; ++kk)
                pf[kk] = bload(&Plds[wave][cl][kk * 32 + g * 8]);
            // ---- PV accumulate ----
#pragma unroll
            for (int n = 0; n < 4; ++n)
#pragma unroll
                for (int kk = 0; kk < 4; ++kk)
                    oacc[n] = __builtin_amdgcn_mfma_f32_16x16x32_bf16(pf[kk], vf[kk][n], oacc[n], 0, 0, 0);
            LGKM0;
            __builtin_amdgcn_s_barrier();
            buf ^= 1;
        }
        // ---- epilogue ----
#pragma unroll
        for (int r = 0; r < 4; ++r) {
            float inv = 1.f / lrow[r];
            int t = q0 + g * 4 + r;
#pragma unroll
            for (int n = 0; n < 4; ++n)
                AO[((size_t)b * T_ + t) * C_ + h * D_ + n * 16 + cl] =
                    f2bf_hw(oacc[n][r] * inv);
        }
    }
}

extern "C" void kernel_launch(void* const* d_in, const int* in_sizes, int n_in,
                              void* d_out, int out_size, void* d_ws, size_t ws_size,
                              hipStream_t stream) {
    (void)in_sizes; (void)n_in; (void)out_size; (void)ws_size;
    const float* x      = (const float*)d_in[0];
    const float* w_attn = (const float*)d_in[1];
    const float* b_attn = (const float*)d_in[2];
    const float* w_proj = (const float*)d_in[3];
    const float* b_proj = (const float*)d_in[4];
    float* out = (float*)d_out;

    char* ws = (char*)d_ws;
    unsigned short* Xb  = (unsigned short*)(ws);
    unsigned short* Wt1 = (unsigned short*)(ws + ((size_t)8  << 20));
    unsigned short* Wt2 = (unsigned short*)(ws + ((size_t)14 << 20));
    unsigned short* Qb  = (unsigned short*)(ws + ((size_t)16 << 20));
    unsigned short* Kb  = (unsigned short*)(ws + ((size_t)24 << 20));
    unsigned short* Vt  = (unsigned short*)(ws + ((size_t)32 << 20));
    unsigned short* AO  = Xb;  // Xb dead after gemm_qkv

    cast_x_kernel<<<1024, 256, 0, stream>>>(x, Xb, (M1 * K_) / 4);
    transpose_cast_kernel<<<dim3(N1 / 32, K_ / 32), 256, 0, stream>>>(w_attn, Wt1, K_, N1);
    transpose_cast_kernel<<<dim3(C_ / 32, K_ / 32), 256, 0, stream>>>(w_proj, Wt2, K_, C_);
    gemm_qkv_kernel<<<dim3(M1 / 128, N1 / 128), 256, 0, stream>>>(Xb, Wt1, b_attn, Qb, Kb, Vt);
    attn_kernel<<<dim3(16, B_ * H_), 256, 0, stream>>>(Qb, Kb, Vt, AO);
    gemm_proj_kernel<<<dim3(M1 / 128, C_ / 128), 256, 0, stream>>>(AO, Wt2, b_proj, out);
}

// Round 7
// 136.489 us; speedup vs baseline: 1.1853x; 1.1853x over previous
//
#include <hip/hip_runtime.h>
#include <hip/hip_bf16.h>

#define B_ 2
#define T_ 2048
#define C_ 1024
#define H_ 16
#define D_ 64
#define M1 4096
#define N1 3072
#define K_ 1024

typedef __attribute__((ext_vector_type(8))) __bf16 bf16x8;
typedef __attribute__((ext_vector_type(4))) float f32x4;
typedef __attribute__((ext_vector_type(8))) unsigned short ushort8_t;
typedef __attribute__((ext_vector_type(4))) unsigned short ushort4_t;
typedef __attribute__((ext_vector_type(2))) unsigned int uint2_t;

static __device__ __forceinline__ unsigned short f2bf(float f) {
    unsigned int u = __builtin_bit_cast(unsigned int, f);
    u += 0x7fffu + ((u >> 16) & 1u);
    return (unsigned short)(u >> 16);
}
static __device__ __forceinline__ unsigned short f2bf_hw(float f) {
    return __builtin_bit_cast(unsigned short, (__bf16)f);
}
static __device__ __forceinline__ unsigned int packbf(float lo, float hi) {
    return (unsigned int)f2bf_hw(lo) | ((unsigned int)f2bf_hw(hi) << 16);
}
static __device__ __forceinline__ bf16x8 bload(const unsigned short* p) {
    return __builtin_bit_cast(bf16x8, *(const ushort8_t*)p);
}

// fast exp2 -> v_exp_f32
#if defined(__has_builtin)
#if __has_builtin(__builtin_amdgcn_exp2f)
#define HAVE_EXP2_BUILTIN 1
#endif
#endif
static __device__ __forceinline__ float fexp2(float x) {
#ifdef HAVE_EXP2_BUILTIN
    return __builtin_amdgcn_exp2f(x);
#else
    float r; asm("v_exp_f32 %0, %1" : "=v"(r) : "v"(x)); return r;
#endif
}

// ---- async global->LDS (16B per lane; LDS dest wave-uniform base + lane*16) ----
typedef __attribute__((address_space(1))) const unsigned int gu32;
typedef __attribute__((address_space(3))) unsigned int lu32;
static __device__ __forceinline__ void gld16(const void* g, void* l) {
    __builtin_amdgcn_global_load_lds((gu32*)g, (lu32*)l, 16, 0, 0);
}

#define VMCNT(n) asm volatile("s_waitcnt vmcnt(" #n ")" ::: "memory")
#define LGKM0    asm volatile("s_waitcnt lgkmcnt(0)" ::: "memory")

// ---------------- cast x -> bf16 ----------------
__global__ void cast_x_kernel(const float* __restrict__ in,
                              unsigned short* __restrict__ out, int n4) {
    int idx = blockIdx.x * blockDim.x + threadIdx.x;
    int stride = gridDim.x * blockDim.x;
    for (int i = idx; i < n4; i += stride) {
        float4 v = ((const float4*)in)[i];
        ushort4_t o;
        o.x = f2bf(v.x); o.y = f2bf(v.y); o.z = f2bf(v.z); o.w = f2bf(v.w);
        ((ushort4_t*)out)[i] = o;
    }
}

// ------------- transpose f32[K][N] -> bf16[N][K] -------------
__global__ void transpose_cast_kernel(const float* __restrict__ in,
                                      unsigned short* __restrict__ out,
                                      int K, int N) {
    __shared__ float tile[32][33];
    int tx = threadIdx.x & 31;
    int ty = threadIdx.x >> 5;
    int n0 = blockIdx.x * 32;
    int k0 = blockIdx.y * 32;
#pragma unroll
    for (int rr = 0; rr < 32; rr += 8)
        tile[ty + rr][tx] = in[(size_t)(k0 + ty + rr) * N + n0 + tx];
    __syncthreads();
#pragma unroll
    for (int rr = 0; rr < 32; rr += 8)
        out[(size_t)(n0 + ty + rr) * K + k0 + tx] = f2bf(tile[tx][ty + rr]);
}

// =================== GEMM common body (dbuf LDS via global_load_lds) ===================

#define GEMM_PROLOGUE()                                                                  \
    __shared__ unsigned short As[2][128 * 32];                                           \
    __shared__ unsigned short Bs[2][128 * 32];                                           \
    const int tid = threadIdx.x;                                                         \
    const int lane = tid & 63;                                                           \
    const int wave = tid >> 6;                                                           \
    const int g = lane >> 4, cl = lane & 15;                                             \
    const int wr = (wave >> 1) * 64, wc = (wave & 1) * 64;                               \
    const int row0 = blockIdx.x * 128;                                                   \
    const int col0 = blockIdx.y * 128;                                                   \
    const int srow = tid >> 2;  /* 0..63 */                                              \
    const int sgran = tid & 3;                                                           \
    f32x4 acc[4][4];                                                                     \
    _Pragma("unroll") for (int m = 0; m < 4; ++m)                                        \
        _Pragma("unroll") for (int n = 0; n < 4; ++n)                                    \
            acc[m][n] = (f32x4){0.f, 0.f, 0.f, 0.f};                                     \
    auto stage = [&](int buf, int k0) {                                                  \
        _Pragma("unroll") for (int c = 0; c < 2; ++c) {                                  \
            int r = srow + c * 64;                                                       \
            gld16(A + (size_t)(row0 + r) * K_ + k0 + sgran * 8,                          \
                  (char*)&As[buf][0] + c * 4096 + wave * 1024);                          \
            gld16(Bt + (size_t)(col0 + r) * K_ + k0 + sgran * 8,                         \
                  (char*)&Bs[buf][0] + c * 4096 + wave * 1024);                          \
        }                                                                                \
    };                                                                                   \
    stage(0, 0);                                                                         \
    int buf = 0;                                                                         \
    for (int k0 = 0; k0 < K_; k0 += 32) {                                                \
        if (k0 + 32 < K_) { stage(buf ^ 1, k0 + 32); VMCNT(4); }                         \
        else              { VMCNT(0); }                                                  \
        __builtin_amdgcn_s_barrier();                                                    \
        bf16x8 af[4], bfv[4];                                                            \
        _Pragma("unroll") for (int m = 0; m < 4; ++m)                                    \
            af[m] = bload(&As[buf][(wr + m * 16 + cl) * 32 + g * 8]);                    \
        _Pragma("unroll") for (int n = 0; n < 4; ++n)                                    \
            bfv[n] = bload(&Bs[buf][(wc + n * 16 + cl) * 32 + g * 8]);                   \
        _Pragma("unroll") for (int m = 0; m < 4; ++m)                                    \
            _Pragma("unroll") for (int n = 0; n < 4; ++n)                                \
                acc[m][n] = __builtin_amdgcn_mfma_f32_16x16x32_bf16(                     \
                    af[m], bfv[n], acc[m][n], 0, 0, 0);                                  \
        LGKM0;                                                                           \
        __builtin_amdgcn_s_barrier();                                                    \
        buf ^= 1;                                                                        \
    }

// ---------------- GEMM1: qkv = Xb @ Wt1^T + b ----------------
__global__ __launch_bounds__(256)
void gemm_qkv_kernel(const unsigned short* __restrict__ A,   // [4096][1024] bf16
                     const unsigned short* __restrict__ Bt,  // [3072][1024] bf16
                     const float* __restrict__ bias,         // [3072]
                     unsigned short* __restrict__ Qo,        // [BH][T][D] (pre-scaled)
                     unsigned short* __restrict__ Ko,        // [BH][T][D]
                     unsigned short* __restrict__ Vt)        // [BH][D][T]
{
    GEMM_PROLOGUE()

    const float QSCALE = 0.125f * 1.44269504088896340736f;  // 1/sqrt(D) * log2(e)
#pragma unroll
    for (int m = 0; m < 4; ++m) {
        int i0 = row0 + wr + m * 16 + g * 4;
#pragma unroll
        for (int n = 0; n < 4; ++n) {
            int j = col0 + wc + n * 16 + cl;
            int which = j >> 10;
            int c = j & 1023;
            int h = c >> 6, d = c & 63;
            float bv = bias[j];
#pragma unroll
            for (int r = 0; r < 4; ++r) {
                int i = i0 + r;
                int b = i >> 11, t = i & 2047;
                size_t bh = (size_t)(b * H_ + h);
                float val = acc[m][n][r] + bv;
                if (which == 0) {
                    Qo[(bh * T_ + t) * D_ + d] = f2bf(val * QSCALE);
                } else if (which == 1) {
                    Ko[(bh * T_ + t) * D_ + d] = f2bf(val);
                } else {
                    Vt[(bh * D_ + d) * T_ + t] = f2bf(val);
                }
            }
        }
    }
}

// ---------------- GEMM2: out = AO @ Wt2^T + b (fp32 out) ----------------
__global__ __launch_bounds__(256)
void gemm_proj_kernel(const unsigned short* __restrict__ A,   // [4096][1024] bf16
                      const unsigned short* __restrict__ Bt,  // [1024][1024] bf16
                      const float* __restrict__ bias,         // [1024]
                      float* __restrict__ out)                // [4096][1024] f32
{
    GEMM_PROLOGUE()

#pragma unroll
    for (int m = 0; m < 4; ++m) {
        int i0 = row0 + wr + m * 16 + g * 4;
#pragma unroll
        for (int n = 0; n < 4; ++n) {
            int j = col0 + wc + n * 16 + cl;
            float bv = bias[j];
#pragma unroll
            for (int r = 0; r < 4; ++r)
                out[(size_t)(i0 + r) * C_ + j] = acc[m][n][r] + bv;
        }
    }
}

// ---------------- flash attention (causal, pair-balanced, swapped QK^T) ----------------
// grid (16, 32): block p handles q-tiles p and 31-p -> exactly 33 kt-steps/block.
// K/V 64x64 tiles in LDS (dbuf, XOR-swizzled, global_load_lds, counted vmcnt(4)).
// SWAPPED operands: S^T = mfma(K,Q) -> lane owns full q-row (q = q0+cl):
// softmax = per-lane serial + 2 shfl_xor; P packed & written as 4x ds_write_b64;
// PV computes O^T = mfma(V^T, P^T). Scores pre-scaled by log2(e)/8 -> exp2 domain.
__global__ __launch_bounds__(256)
void attn_kernel(const unsigned short* __restrict__ Q,   // [BH][T][D], pre-scaled
                 const unsigned short* __restrict__ Kb,  // [BH][T][D]
                 const unsigned short* __restrict__ Vh_, // [BH][D][T]
                 unsigned short* __restrict__ AO)        // [B][T][C] bf16
{
    __shared__ unsigned short Klds[2][64 * 64];   // 16 KB
    __shared__ unsigned short Vlds[2][64 * 64];   // 16 KB
    __shared__ unsigned short Plds[4][16][72];    // per-wave P rows, 9 KB
    const int pair = blockIdx.x;  // 0..15
    const int bh = blockIdx.y;    // 0..31
    const int b = bh >> 4, h = bh & 15;
    const int tid = threadIdx.x;
    const int lane = tid & 63;
    const int wave = tid >> 6;
    const int g = lane >> 4, cl = lane & 15;

    const unsigned short* Qh = Q + (size_t)bh * T_ * D_;
    const unsigned short* Kh = Kb + (size_t)bh * T_ * D_;
    const unsigned short* Vh = Vh_ + (size_t)bh * D_ * T_;

    const int srow = tid >> 3;  // 0..31
    const int sg   = tid & 7;

    // stage one 64x64 K tile + one 64x64 V^T tile; granule pre-swizzled lg = sg ^ (r&7)
    auto stage = [&](int bufi, int kb) {
#pragma unroll
        for (int c = 0; c < 2; ++c) {
            int r = srow + c * 32;
            int lg = sg ^ (r & 7);
            gld16(Kh + (size_t)(kb + r) * D_ + lg * 8,
                  (char*)&Klds[bufi][0] + c * 4096 + wave * 1024);
            gld16(Vh + (size_t)r * T_ + kb + lg * 8,
                  (char*)&Vlds[bufi][0] + c * 4096 + wave * 1024);
        }
    };

    for (int half = 0; half < 2; ++half) {
        const int qt = half ? (31 - pair) : pair;
        const int q0 = qt * 64 + wave * 16;
        const int tq = q0 + cl;   // this lane's q row

        bf16x8 qf[2];
#pragma unroll
        for (int c2 = 0; c2 < 2; ++c2)
            qf[c2] = bload(Qh + (size_t)(q0 + cl) * D_ + c2 * 32 + g * 8);

        f32x4 oacc[4];
#pragma unroll
        for (int n = 0; n < 4; ++n) oacc[n] = (f32x4){0.f, 0.f, 0.f, 0.f};
        float m_run = -INFINITY, l_run = 0.f;

        const int nk = qt + 1;
        stage(0, 0);
        int buf = 0;
        for (int kt = 0; kt < nk; ++kt) {
            if (kt + 1 < nk) { stage(buf ^ 1, (kt + 1) * 64); VMCNT(4); }
            else             { VMCNT(0); }
            __builtin_amdgcn_s_barrier();

            const int kb = kt * 64;
            // ---- QK^T (swapped): sc[n] row = k, col = q ----
            f32x4 sc[4];
            __builtin_amdgcn_s_setprio(1);
#pragma unroll
            for (int n = 0; n < 4; ++n) {
                sc[n] = (f32x4){0.f, 0.f, 0.f, 0.f};
#pragma unroll
                for (int c2 = 0; c2 < 2; ++c2) {
                    int pg = (c2 * 4 + g) ^ (cl & 7);
                    bf16x8 kf = bload(&Klds[buf][(n * 16 + cl) * 64 + pg * 8]);
                    sc[n] = __builtin_amdgcn_mfma_f32_16x16x32_bf16(kf, qf[c2], sc[n], 0, 0, 0);
                }
            }
            __builtin_amdgcn_s_setprio(0);
            // ---- causal mask (diagonal tile only); k = kb + n*16 + g*4 + r ----
            if (kt == qt) {
#pragma unroll
                for (int n = 0; n < 4; ++n) {
                    int k4 = kb + n * 16 + g * 4;
#pragma unroll
                    for (int r = 0; r < 4; ++r)
                        if (k4 + r > tq) sc[n][r] = -INFINITY;
                }
            }
            // ---- online softmax: per-lane 16 values + 2 shfl_xor across g ----
            float vmax = sc[0][0];
#pragma unroll
            for (int n = 0; n < 4; ++n)
#pragma unroll
                for (int r = 0; r < 4; ++r) vmax = fmaxf(vmax, sc[n][r]);
            vmax = fmaxf(vmax, __shfl_xor(vmax, 16, 64));
            vmax = fmaxf(vmax, __shfl_xor(vmax, 32, 64));
            float mn = fmaxf(m_run, vmax);
            float alpha = fexp2(m_run - mn);
            float p[4][4];
            float ps = 0.f;
#pragma unroll
            for (int n = 0; n < 4; ++n)
#pragma unroll
                for (int r = 0; r < 4; ++r) { p[n][r] = fexp2(sc[n][r] - mn); ps += p[n][r]; }
            ps += __shfl_xor(ps, 16, 64);
            ps += __shfl_xor(ps, 32, 64);
            l_run = l_run * alpha + ps;
            m_run = mn;
#pragma unroll
            for (int n = 0; n < 4; ++n)
#pragma unroll
                for (int r = 0; r < 4; ++r) oacc[n][r] *= alpha;
            // ---- P: pack bf16 pairs, 4x ds_write_b64 into own q-row ----
#pragma unroll
            for (int n = 0; n < 4; ++n) {
                uint2_t w;
                w.x = packbf(p[n][0], p[n][1]);
                w.y = packbf(p[n][2], p[n][3]);
                *(uint2_t*)&Plds[wave][cl][n * 16 + g * 4] = w;
            }
            bf16x8 pf[2];
#pragma unroll
            for (int kk = 0; kk < 2; ++kk)
                pf[kk] = bload(&Plds[wave][cl][kk * 32 + g * 8]);
            // ---- PV (swapped): O^T += mfma(V^T-frag, P^T-frag) ----
            __builtin_amdgcn_s_setprio(1);
#pragma unroll
            for (int n = 0; n < 4; ++n) {
#pragma unroll
                for (int kk = 0; kk < 2; ++kk) {
                    int pg = (kk * 4 + g) ^ (cl & 7);
                    bf16x8 vfr = bload(&Vlds[buf][(n * 16 + cl) * 64 + pg * 8]);
                    oacc[n] = __builtin_amdgcn_mfma_f32_16x16x32_bf16(vfr, pf[kk], oacc[n], 0, 0, 0);
                }
            }
            __builtin_amdgcn_s_setprio(0);
            LGKM0;
            __builtin_amdgcn_s_barrier();
            buf ^= 1;
        }
        // ---- epilogue: lane owns row t = q0+cl; d = n*16 + g*4 + r ----
        float inv = 1.f / l_run;
#pragma unroll
        for (int n = 0; n < 4; ++n) {
            uint2_t w;
            w.x = packbf(oacc[n][0] * inv, oacc[n][1] * inv);
            w.y = packbf(oacc[n][2] * inv, oacc[n][3] * inv);
            *(uint2_t*)&AO[((size_t)b * T_ + tq) * C_ + h * D_ + n * 16 + g * 4] = w;
        }
    }
}

extern "C" void kernel_launch(void* const* d_in, const int* in_sizes, int n_in,
                              void* d_out, int out_size, void* d_ws, size_t ws_size,
                              hipStream_t stream) {
    (void)in_sizes; (void)n_in; (void)out_size; (void)ws_size;
    const float* x      = (const float*)d_in[0];
    const float* w_attn = (const float*)d_in[1];
    const float* b_attn = (const float*)d_in[2];
    const float* w_proj = (const float*)d_in[3];
    const float* b_proj = (const float*)d_in[4];
    float* out = (float*)d_out;

    char* ws = (char*)d_ws;
    unsigned short* Xb  = (unsigned short*)(ws);
    unsigned short* Wt1 = (unsigned short*)(ws + ((size_t)8  << 20));
    unsigned short* Wt2 = (unsigned short*)(ws + ((size_t)14 << 20));
    unsigned short* Qb  = (unsigned short*)(ws + ((size_t)16 << 20));
    unsigned short* Kb  = (unsigned short*)(ws + ((size_t)24 << 20));
    unsigned short* Vt  = (unsigned short*)(ws + ((size_t)32 << 20));
    unsigned short* AO  = Xb;  // Xb dead after gemm_qkv

    cast_x_kernel<<<1024, 256, 0, stream>>>(x, Xb, (M1 * K_) / 4);
    transpose_cast_kernel<<<dim3(N1 / 32, K_ / 32), 256, 0, stream>>>(w_attn, Wt1, K_, N1);
    transpose_cast_kernel<<<dim3(C_ / 32, K_ / 32), 256, 0, stream>>>(w_proj, Wt2, K_, C_);
    gemm_qkv_kernel<<<dim3(M1 / 128, N1 / 128), 256, 0, stream>>>(Xb, Wt1, b_attn, Qb, Kb, Vt);
    attn_kernel<<<dim3(16, B_ * H_), 256, 0, stream>>>(Qb, Kb, Vt, AO);
    gemm_proj_kernel<<<dim3(M1 / 128, C_ / 128), 256, 0, stream>>>(AO, Wt2, b_proj, out);
}

// Round 8
// 133.459 us; speedup vs baseline: 1.2122x; 1.0227x over previous
//
#include <hip/hip_runtime.h>
#include <hip/hip_bf16.h>

#define B_ 2
#define T_ 2048
#define C_ 1024
#define H_ 16
#define D_ 64
#define M1 4096
#define N1 3072
#define K_ 1024

typedef __attribute__((ext_vector_type(8))) __bf16 bf16x8;
typedef __attribute__((ext_vector_type(4))) float f32x4;
typedef __attribute__((ext_vector_type(8))) unsigned short ushort8_t;
typedef __attribute__((ext_vector_type(4))) unsigned short ushort4_t;
typedef __attribute__((ext_vector_type(2))) unsigned int uint2_t;

static __device__ __forceinline__ unsigned short f2bf(float f) {
    unsigned int u = __builtin_bit_cast(unsigned int, f);
    u += 0x7fffu + ((u >> 16) & 1u);
    return (unsigned short)(u >> 16);
}
static __device__ __forceinline__ unsigned short f2bf_hw(float f) {
    return __builtin_bit_cast(unsigned short, (__bf16)f);
}
static __device__ __forceinline__ unsigned int packbf(float lo, float hi) {
    return (unsigned int)f2bf_hw(lo) | ((unsigned int)f2bf_hw(hi) << 16);
}
static __device__ __forceinline__ bf16x8 bload(const unsigned short* p) {
    return __builtin_bit_cast(bf16x8, *(const ushort8_t*)p);
}

// fast exp2 -> v_exp_f32
#if defined(__has_builtin)
#if __has_builtin(__builtin_amdgcn_exp2f)
#define HAVE_EXP2_BUILTIN 1
#endif
#endif
static __device__ __forceinline__ float fexp2(float x) {
#ifdef HAVE_EXP2_BUILTIN
    return __builtin_amdgcn_exp2f(x);
#else
    float r; asm("v_exp_f32 %0, %1" : "=v"(r) : "v"(x)); return r;
#endif
}

// ---- async global->LDS (16B per lane; LDS dest wave-uniform base + lane*16) ----
typedef __attribute__((address_space(1))) const unsigned int gu32;
typedef __attribute__((address_space(3))) unsigned int lu32;
static __device__ __forceinline__ void gld16(const void* g, void* l) {
    __builtin_amdgcn_global_load_lds((gu32*)g, (lu32*)l, 16, 0, 0);
}

#define VMCNT(n) asm volatile("s_waitcnt vmcnt(" #n ")" ::: "memory")
#define LGKM0    asm volatile("s_waitcnt lgkmcnt(0)" ::: "memory")

// ---------------- cast x -> bf16 ----------------
__global__ void cast_x_kernel(const float* __restrict__ in,
                              unsigned short* __restrict__ out, int n4) {
    int idx = blockIdx.x * blockDim.x + threadIdx.x;
    int stride = gridDim.x * blockDim.x;
    for (int i = idx; i < n4; i += stride) {
        float4 v = ((const float4*)in)[i];
        ushort4_t o;
        o.x = f2bf(v.x); o.y = f2bf(v.y); o.z = f2bf(v.z); o.w = f2bf(v.w);
        ((ushort4_t*)out)[i] = o;
    }
}

// ------------- transpose f32[K][N] -> bf16[N][K] -------------
__global__ void transpose_cast_kernel(const float* __restrict__ in,
                                      unsigned short* __restrict__ out,
                                      int K, int N) {
    __shared__ float tile[32][33];
    int tx = threadIdx.x & 31;
    int ty = threadIdx.x >> 5;
    int n0 = blockIdx.x * 32;
    int k0 = blockIdx.y * 32;
#pragma unroll
    for (int rr = 0; rr < 32; rr += 8)
        tile[ty + rr][tx] = in[(size_t)(k0 + ty + rr) * N + n0 + tx];
    __syncthreads();
#pragma unroll
    for (int rr = 0; rr < 32; rr += 8)
        out[(size_t)(n0 + ty + rr) * K + k0 + tx] = f2bf(tile[tx][ty + rr]);
}

// =================== GEMM common body (dbuf LDS via global_load_lds) ===================
// BXE/BYE: block tile indices (possibly XCD-remapped by the caller).

#define GEMM_PROLOGUE(BXE, BYE)                                                          \
    __shared__ unsigned short As[2][128 * 32];                                           \
    __shared__ unsigned short Bs[2][128 * 32];                                           \
    const int tid = threadIdx.x;                                                         \
    const int lane = tid & 63;                                                           \
    const int wave = tid >> 6;                                                           \
    const int g = lane >> 4, cl = lane & 15;                                             \
    const int wr = (wave >> 1) * 64, wc = (wave & 1) * 64;                               \
    const int row0 = (BXE) * 128;                                                        \
    const int col0 = (BYE) * 128;                                                        \
    const int srow = tid >> 2;  /* 0..63 */                                              \
    const int sgran = tid & 3;                                                           \
    f32x4 acc[4][4];                                                                     \
    _Pragma("unroll") for (int m = 0; m < 4; ++m)                                        \
        _Pragma("unroll") for (int n = 0; n < 4; ++n)                                    \
            acc[m][n] = (f32x4){0.f, 0.f, 0.f, 0.f};                                     \
    auto stage = [&](int buf, int k0) {                                                  \
        _Pragma("unroll") for (int c = 0; c < 2; ++c) {                                  \
            int r = srow + c * 64;                                                       \
            gld16(A + (size_t)(row0 + r) * K_ + k0 + sgran * 8,                          \
                  (char*)&As[buf][0] + c * 4096 + wave * 1024);                          \
            gld16(Bt + (size_t)(col0 + r) * K_ + k0 + sgran * 8,                         \
                  (char*)&Bs[buf][0] + c * 4096 + wave * 1024);                          \
        }                                                                                \
    };                                                                                   \
    stage(0, 0);                                                                         \
    int buf = 0;                                                                         \
    for (int k0 = 0; k0 < K_; k0 += 32) {                                                \
        if (k0 + 32 < K_) { stage(buf ^ 1, k0 + 32); VMCNT(4); }                         \
        else              { VMCNT(0); }                                                  \
        __builtin_amdgcn_s_barrier();                                                    \
        bf16x8 af[4], bfv[4];                                                            \
        _Pragma("unroll") for (int m = 0; m < 4; ++m)                                    \
            af[m] = bload(&As[buf][(wr + m * 16 + cl) * 32 + g * 8]);                    \
        _Pragma("unroll") for (int n = 0; n < 4; ++n)                                    \
            bfv[n] = bload(&Bs[buf][(wc + n * 16 + cl) * 32 + g * 8]);                   \
        _Pragma("unroll") for (int m = 0; m < 4; ++m)                                    \
            _Pragma("unroll") for (int n = 0; n < 4; ++n)                                \
                acc[m][n] = __builtin_amdgcn_mfma_f32_16x16x32_bf16(                     \
                    af[m], bfv[n], acc[m][n], 0, 0, 0);                                  \
        LGKM0;                                                                           \
        __builtin_amdgcn_s_barrier();                                                    \
        buf ^= 1;                                                                        \
    }

// ---------------- GEMM1: qkv = Xb @ Wt1^T + b ----------------
// XCD-chunked block map: grid 32x24 = 512-aligned linear ids round-robin XCDs;
// give each XCD an 8-row x 12-col region -> per-XCD fetch 2MB A + 3MB B.
__global__ __launch_bounds__(256)
void gemm_qkv_kernel(const unsigned short* __restrict__ A,   // [4096][1024] bf16
                     const unsigned short* __restrict__ Bt,  // [3072][1024] bf16
                     const float* __restrict__ bias,         // [3072]
                     unsigned short* __restrict__ Qo,        // [BH][T][D] (pre-scaled)
                     unsigned short* __restrict__ Ko,        // [BH][T][D]
                     unsigned short* __restrict__ Vt)        // [BH][D][T]
{
    const int lin = blockIdx.x + gridDim.x * blockIdx.y;  // 0..767
    const int xcd = lin & 7;
    const int idx = lin >> 3;                              // 0..95
    const int bx = (xcd >> 1) * 8 + (idx & 7);             // 0..31
    const int by = (xcd & 1) * 12 + (idx >> 3);            // 0..23

    GEMM_PROLOGUE(bx, by)

    const float QSCALE = 0.125f * 1.44269504088896340736f;  // 1/sqrt(D) * log2(e)
#pragma unroll
    for (int m = 0; m < 4; ++m) {
        int i0 = row0 + wr + m * 16 + g * 4;
#pragma unroll
        for (int n = 0; n < 4; ++n) {
            int j = col0 + wc + n * 16 + cl;
            int which = j >> 10;
            int c = j & 1023;
            int h = c >> 6, d = c & 63;
            float bv = bias[j];
#pragma unroll
            for (int r = 0; r < 4; ++r) {
                int i = i0 + r;
                int b = i >> 11, t = i & 2047;
                size_t bh = (size_t)(b * H_ + h);
                float val = acc[m][n][r] + bv;
                if (which == 0) {
                    Qo[(bh * T_ + t) * D_ + d] = f2bf(val * QSCALE);
                } else if (which == 1) {
                    Ko[(bh * T_ + t) * D_ + d] = f2bf(val);
                } else {
                    Vt[(bh * D_ + d) * T_ + t] = f2bf(val);
                }
            }
        }
    }
}

// ---------------- GEMM2: out = AO @ Wt2^T + b (fp32 out) ----------------
__global__ __launch_bounds__(256)
void gemm_proj_kernel(const unsigned short* __restrict__ A,   // [4096][1024] bf16
                      const unsigned short* __restrict__ Bt,  // [1024][1024] bf16
                      const float* __restrict__ bias,         // [1024]
                      float* __restrict__ out)                // [4096][1024] f32
{
    GEMM_PROLOGUE(blockIdx.x, blockIdx.y)

#pragma unroll
    for (int m = 0; m < 4; ++m) {
        int i0 = row0 + wr + m * 16 + g * 4;
#pragma unroll
        for (int n = 0; n < 4; ++n) {
            int j = col0 + wc + n * 16 + cl;
            float bv = bias[j];
#pragma unroll
            for (int r = 0; r < 4; ++r)
                out[(size_t)(i0 + r) * C_ + j] = acc[m][n][r] + bv;
        }
    }
}

// ---------------- flash attention (causal, pair-balanced, swapped QK^T) ----------------
// grid (16, 32) = 512 blocks. Block map is XCD-aware: lin%8 == XCD (round-robin
// dispatch), so choose bh = (lin&7) + 8*(lin>>7): all 16 pair-blocks of a head
// share one XCD; each XCD serves 4 heads = 2MB K/V, L2-resident. pair = (lin>>3)&15.
// Exactly 33 kt-steps per block (pair-balance). K/V LDS dbuf via global_load_lds,
// counted vmcnt(4), XOR-swizzle. Swapped operands: lane owns q-row; softmax is
// per-lane + 2 shfl_xor. Scores pre-scaled by log2(e)/8 -> exp2 domain.
__global__ __launch_bounds__(256)
void attn_kernel(const unsigned short* __restrict__ Q,   // [BH][T][D], pre-scaled
                 const unsigned short* __restrict__ Kb,  // [BH][T][D]
                 const unsigned short* __restrict__ Vh_, // [BH][D][T]
                 unsigned short* __restrict__ AO)        // [B][T][C] bf16
{
    __shared__ unsigned short Klds[2][64 * 64];   // 16 KB
    __shared__ unsigned short Vlds[2][64 * 64];   // 16 KB
    __shared__ unsigned short Plds[4][16][72];    // per-wave P rows, 9 KB
    const int lin = blockIdx.x + 16 * blockIdx.y;  // 0..511
    const int pair = (lin >> 3) & 15;              // 0..15
    const int bh = (lin & 7) + 8 * (lin >> 7);     // 0..31, XCD-local per head
    const int b = bh >> 4, h = bh & 15;
    const int tid = threadIdx.x;
    const int lane = tid & 63;
    const int wave = tid >> 6;
    const int g = lane >> 4, cl = lane & 15;

    const unsigned short* Qh = Q + (size_t)bh * T_ * D_;
    const unsigned short* Kh = Kb + (size_t)bh * T_ * D_;
    const unsigned short* Vh = Vh_ + (size_t)bh * D_ * T_;

    const int srow = tid >> 3;  // 0..31
    const int sg   = tid & 7;

    // stage one 64x64 K tile + one 64x64 V^T tile; granule pre-swizzled lg = sg ^ (r&7)
    auto stage = [&](int bufi, int kb) {
#pragma unroll
        for (int c = 0; c < 2; ++c) {
            int r = srow + c * 32;
            int lg = sg ^ (r & 7);
            gld16(Kh + (size_t)(kb + r) * D_ + lg * 8,
                  (char*)&Klds[bufi][0] + c * 4096 + wave * 1024);
            gld16(Vh + (size_t)r * T_ + kb + lg * 8,
                  (char*)&Vlds[bufi][0] + c * 4096 + wave * 1024);
        }
    };

    for (int half = 0; half < 2; ++half) {
        const int qt = half ? (31 - pair) : pair;
        const int q0 = qt * 64 + wave * 16;
        const int tq = q0 + cl;   // this lane's q row

        bf16x8 qf[2];
#pragma unroll
        for (int c2 = 0; c2 < 2; ++c2)
            qf[c2] = bload(Qh + (size_t)(q0 + cl) * D_ + c2 * 32 + g * 8);

        f32x4 oacc[4];
#pragma unroll
        for (int n = 0; n < 4; ++n) oacc[n] = (f32x4){0.f, 0.f, 0.f, 0.f};
        float m_run = -INFINITY, l_run = 0.f;

        const int nk = qt + 1;
        stage(0, 0);
        int buf = 0;
        for (int kt = 0; kt < nk; ++kt) {
            if (kt + 1 < nk) { stage(buf ^ 1, (kt + 1) * 64); VMCNT(4); }
            else             { VMCNT(0); }
            __builtin_amdgcn_s_barrier();

            const int kb = kt * 64;
            // ---- QK^T (swapped): sc[n] row = k, col = q ----
            f32x4 sc[4];
            __builtin_amdgcn_s_setprio(1);
#pragma unroll
            for (int n = 0; n < 4; ++n) {
                sc[n] = (f32x4){0.f, 0.f, 0.f, 0.f};
#pragma unroll
                for (int c2 = 0; c2 < 2; ++c2) {
                    int pg = (c2 * 4 + g) ^ (cl & 7);
                    bf16x8 kf = bload(&Klds[buf][(n * 16 + cl) * 64 + pg * 8]);
                    sc[n] = __builtin_amdgcn_mfma_f32_16x16x32_bf16(kf, qf[c2], sc[n], 0, 0, 0);
                }
            }
            __builtin_amdgcn_s_setprio(0);
            // ---- causal mask (diagonal tile only); k = kb + n*16 + g*4 + r ----
            if (kt == qt) {
#pragma unroll
                for (int n = 0; n < 4; ++n) {
                    int k4 = kb + n * 16 + g * 4;
#pragma unroll
                    for (int r = 0; r < 4; ++r)
                        if (k4 + r > tq) sc[n][r] = -INFINITY;
                }
            }
            // ---- online softmax: per-lane 16 values + 2 shfl_xor across g ----
            float vmax = sc[0][0];
#pragma unroll
            for (int n = 0; n < 4; ++n)
#pragma unroll
                for (int r = 0; r < 4; ++r) vmax = fmaxf(vmax, sc[n][r]);
            vmax = fmaxf(vmax, __shfl_xor(vmax, 16, 64));
            vmax = fmaxf(vmax, __shfl_xor(vmax, 32, 64));
            float mn = fmaxf(m_run, vmax);
            float alpha = fexp2(m_run - mn);
            float p[4][4];
            float ps = 0.f;
#pragma unroll
            for (int n = 0; n < 4; ++n)
#pragma unroll
                for (int r = 0; r < 4; ++r) { p[n][r] = fexp2(sc[n][r] - mn); ps += p[n][r]; }
            ps += __shfl_xor(ps, 16, 64);
            ps += __shfl_xor(ps, 32, 64);
            l_run = l_run * alpha + ps;
            m_run = mn;
#pragma unroll
            for (int n = 0; n < 4; ++n)
#pragma unroll
                for (int r = 0; r < 4; ++r) oacc[n][r] *= alpha;
            // ---- P: pack bf16 pairs, 4x ds_write_b64 into own q-row ----
#pragma unroll
            for (int n = 0; n < 4; ++n) {
                uint2_t w;
                w.x = packbf(p[n][0], p[n][1]);
                w.y = packbf(p[n][2], p[n][3]);
                *(uint2_t*)&Plds[wave][cl][n * 16 + g * 4] = w;
            }
            bf16x8 pf[2];
#pragma unroll
            for (int kk = 0; kk < 2; ++kk)
                pf[kk] = bload(&Plds[wave][cl][kk * 32 + g * 8]);
            // ---- PV (swapped): O^T += mfma(V^T-frag, P^T-frag) ----
            __builtin_amdgcn_s_setprio(1);
#pragma unroll
            for (int n = 0; n < 4; ++n) {
#pragma unroll
                for (int kk = 0; kk < 2; ++kk) {
                    int pg = (kk * 4 + g) ^ (cl & 7);
                    bf16x8 vfr = bload(&Vlds[buf][(n * 16 + cl) * 64 + pg * 8]);
                    oacc[n] = __builtin_amdgcn_mfma_f32_16x16x32_bf16(vfr, pf[kk], oacc[n], 0, 0, 0);
                }
            }
            __builtin_amdgcn_s_setprio(0);
            LGKM0;
            __builtin_amdgcn_s_barrier();
            buf ^= 1;
        }
        // ---- epilogue: lane owns row t = q0+cl; d = n*16 + g*4 + r ----
        float inv = 1.f / l_run;
#pragma unroll
        for (int n = 0; n < 4; ++n) {
            uint2_t w;
            w.x = packbf(oacc[n][0] * inv, oacc[n][1] * inv);
            w.y = packbf(oacc[n][2] * inv, oacc[n][3] * inv);
            *(uint2_t*)&AO[((size_t)b * T_ + tq) * C_ + h * D_ + n * 16 + g * 4] = w;
        }
    }
}

extern "C" void kernel_launch(void* const* d_in, const int* in_sizes, int n_in,
                              void* d_out, int out_size, void* d_ws, size_t ws_size,
                              hipStream_t stream) {
    (void)in_sizes; (void)n_in; (void)out_size; (void)ws_size;
    const float* x      = (const float*)d_in[0];
    const float* w_attn = (const float*)d_in[1];
    const float* b_attn = (const float*)d_in[2];
    const float* w_proj = (const float*)d_in[3];
    const float* b_proj = (const float*)d_in[4];
    float* out = (float*)d_out;

    char* ws = (char*)d_ws;
    unsigned short* Xb  = (unsigned short*)(ws);
    unsigned short* Wt1 = (unsigned short*)(ws + ((size_t)8  << 20));
    unsigned short* Wt2 = (unsigned short*)(ws + ((size_t)14 << 20));
    unsigned short* Qb  = (unsigned short*)(ws + ((size_t)16 << 20));
    unsigned short* Kb  = (unsigned short*)(ws + ((size_t)24 << 20));
    unsigned short* Vt  = (unsigned short*)(ws + ((size_t)32 << 20));
    unsigned short* AO  = Xb;  // Xb dead after gemm_qkv

    cast_x_kernel<<<1024, 256, 0, stream>>>(x, Xb, (M1 * K_) / 4);
    transpose_cast_kernel<<<dim3(N1 / 32, K_ / 32), 256, 0, stream>>>(w_attn, Wt1, K_, N1);
    transpose_cast_kernel<<<dim3(C_ / 32, K_ / 32), 256, 0, stream>>>(w_proj, Wt2, K_, C_);
    gemm_qkv_kernel<<<dim3(M1 / 128, N1 / 128), 256, 0, stream>>>(Xb, Wt1, b_attn, Qb, Kb, Vt);
    attn_kernel<<<dim3(16, B_ * H_), 256, 0, stream>>>(Qb, Kb, Vt, AO);
    gemm_proj_kernel<<<dim3(M1 / 128, C_ / 128), 256, 0, stream>>>(AO, Wt2, b_proj, out);
}

// Round 9
// 132.956 us; speedup vs baseline: 1.2168x; 1.0038x over previous
//
#include <hip/hip_runtime.h>
#include <hip/hip_bf16.h>

#define B_ 2
#define T_ 2048
#define C_ 1024
#define H_ 16
#define D_ 64
#define M1 4096
#define N1 3072
#define K_ 1024

typedef __attribute__((ext_vector_type(8))) __bf16 bf16x8;
typedef __attribute__((ext_vector_type(4))) float f32x4;
typedef __attribute__((ext_vector_type(8))) unsigned short ushort8_t;
typedef __attribute__((ext_vector_type(4))) unsigned short ushort4_t;
typedef __attribute__((ext_vector_type(2))) unsigned int uint2_t;

static __device__ __forceinline__ unsigned short f2bf(float f) {
    unsigned int u = __builtin_bit_cast(unsigned int, f);
    u += 0x7fffu + ((u >> 16) & 1u);
    return (unsigned short)(u >> 16);
}
static __device__ __forceinline__ unsigned short f2bf_hw(float f) {
    return __builtin_bit_cast(unsigned short, (__bf16)f);
}
static __device__ __forceinline__ unsigned int packbf(float lo, float hi) {
    return (unsigned int)f2bf_hw(lo) | ((unsigned int)f2bf_hw(hi) << 16);
}
static __device__ __forceinline__ bf16x8 bload(const unsigned short* p) {
    return __builtin_bit_cast(bf16x8, *(const ushort8_t*)p);
}

// fast exp2 -> v_exp_f32
#if defined(__has_builtin)
#if __has_builtin(__builtin_amdgcn_exp2f)
#define HAVE_EXP2_BUILTIN 1
#endif
#endif
static __device__ __forceinline__ float fexp2(float x) {
#ifdef HAVE_EXP2_BUILTIN
    return __builtin_amdgcn_exp2f(x);
#else
    float r; asm("v_exp_f32 %0, %1" : "=v"(r) : "v"(x)); return r;
#endif
}

// ---- async global->LDS (16B per lane; LDS dest wave-uniform base + lane*16) ----
typedef __attribute__((address_space(1))) const unsigned int gu32;
typedef __attribute__((address_space(3))) unsigned int lu32;
static __device__ __forceinline__ void gld16(const void* g, void* l) {
    __builtin_amdgcn_global_load_lds((gu32*)g, (lu32*)l, 16, 0, 0);
}

#define VMCNT(n) asm volatile("s_waitcnt vmcnt(" #n ")" ::: "memory")
#define LGKM0    asm volatile("s_waitcnt lgkmcnt(0)" ::: "memory")

// ---------------- cast x -> bf16 ----------------
__global__ void cast_x_kernel(const float* __restrict__ in,
                              unsigned short* __restrict__ out, int n4) {
    int idx = blockIdx.x * blockDim.x + threadIdx.x;
    int stride = gridDim.x * blockDim.x;
    for (int i = idx; i < n4; i += stride) {
        float4 v = ((const float4*)in)[i];
        ushort4_t o;
        o.x = f2bf(v.x); o.y = f2bf(v.y); o.z = f2bf(v.z); o.w = f2bf(v.w);
        ((ushort4_t*)out)[i] = o;
    }
}

// ------------- transpose f32[K][N] -> bf16[N][K] -------------
__global__ void transpose_cast_kernel(const float* __restrict__ in,
                                      unsigned short* __restrict__ out,
                                      int K, int N) {
    __shared__ float tile[32][33];
    int tx = threadIdx.x & 31;
    int ty = threadIdx.x >> 5;
    int n0 = blockIdx.x * 32;
    int k0 = blockIdx.y * 32;
#pragma unroll
    for (int rr = 0; rr < 32; rr += 8)
        tile[ty + rr][tx] = in[(size_t)(k0 + ty + rr) * N + n0 + tx];
    __syncthreads();
#pragma unroll
    for (int rr = 0; rr < 32; rr += 8)
        out[(size_t)(n0 + ty + rr) * K + k0 + tx] = f2bf(tile[tx][ty + rr]);
}

// =================== GEMM common body (dbuf LDS via global_load_lds) ===================
// BXE/BYE: block tile indices (possibly XCD-remapped by the caller).

#define GEMM_PROLOGUE(BXE, BYE)                                                          \
    __shared__ unsigned short As[2][128 * 32];                                           \
    __shared__ unsigned short Bs[2][128 * 32];                                           \
    const int tid = threadIdx.x;                                                         \
    const int lane = tid & 63;                                                           \
    const int wave = tid >> 6;                                                           \
    const int g = lane >> 4, cl = lane & 15;                                             \
    const int wr = (wave >> 1) * 64, wc = (wave & 1) * 64;                               \
    const int row0 = (BXE) * 128;                                                        \
    const int col0 = (BYE) * 128;                                                        \
    const int srow = tid >> 2;  /* 0..63 */                                              \
    const int sgran = tid & 3;                                                           \
    f32x4 acc[4][4];                                                                     \
    _Pragma("unroll") for (int m = 0; m < 4; ++m)                                        \
        _Pragma("unroll") for (int n = 0; n < 4; ++n)                                    \
            acc[m][n] = (f32x4){0.f, 0.f, 0.f, 0.f};                                     \
    auto stage = [&](int buf, int k0) {                                                  \
        _Pragma("unroll") for (int c = 0; c < 2; ++c) {                                  \
            int r = srow + c * 64;                                                       \
            gld16(A + (size_t)(row0 + r) * K_ + k0 + sgran * 8,                          \
                  (char*)&As[buf][0] + c * 4096 + wave * 1024);                          \
            gld16(Bt + (size_t)(col0 + r) * K_ + k0 + sgran * 8,                         \
                  (char*)&Bs[buf][0] + c * 4096 + wave * 1024);                          \
        }                                                                                \
    };                                                                                   \
    stage(0, 0);                                                                         \
    int buf = 0;                                                                         \
    for (int k0 = 0; k0 < K_; k0 += 32) {                                                \
        if (k0 + 32 < K_) { stage(buf ^ 1, k0 + 32); VMCNT(4); }                         \
        else              { VMCNT(0); }                                                  \
        __builtin_amdgcn_s_barrier();                                                    \
        bf16x8 af[4], bfv[4];                                                            \
        _Pragma("unroll") for (int m = 0; m < 4; ++m)                                    \
            af[m] = bload(&As[buf][(wr + m * 16 + cl) * 32 + g * 8]);                    \
        _Pragma("unroll") for (int n = 0; n < 4; ++n)                                    \
            bfv[n] = bload(&Bs[buf][(wc + n * 16 + cl) * 32 + g * 8]);                   \
        _Pragma("unroll") for (int m = 0; m < 4; ++m)                                    \
            _Pragma("unroll") for (int n = 0; n < 4; ++n)                                \
                acc[m][n] = __builtin_amdgcn_mfma_f32_16x16x32_bf16(                     \
                    af[m], bfv[n], acc[m][n], 0, 0, 0);                                  \
        LGKM0;                                                                           \
        __builtin_amdgcn_s_barrier();                                                    \
        buf ^= 1;                                                                        \
    }

// ---------------- GEMM1: qkv = Xb @ Wt1^T + b ----------------
// XCD-chunked block map: per-XCD 8-row x 12-col region.
__global__ __launch_bounds__(256)
void gemm_qkv_kernel(const unsigned short* __restrict__ A,   // [4096][1024] bf16
                     const unsigned short* __restrict__ Bt,  // [3072][1024] bf16
                     const float* __restrict__ bias,         // [3072]
                     unsigned short* __restrict__ Qo,        // [BH][T][D] (pre-scaled)
                     unsigned short* __restrict__ Ko,        // [BH][T][D]
                     unsigned short* __restrict__ Vt)        // [BH][D][T]
{
    const int lin = blockIdx.x + gridDim.x * blockIdx.y;  // 0..767
    const int xcd = lin & 7;
    const int idx = lin >> 3;                              // 0..95
    const int bx = (xcd >> 1) * 8 + (idx & 7);             // 0..31
    const int by = (xcd & 1) * 12 + (idx >> 3);            // 0..23

    GEMM_PROLOGUE(bx, by)

    const float QSCALE = 0.125f * 1.44269504088896340736f;  // 1/sqrt(D) * log2(e)
#pragma unroll
    for (int m = 0; m < 4; ++m) {
        int i0 = row0 + wr + m * 16 + g * 4;
#pragma unroll
        for (int n = 0; n < 4; ++n) {
            int j = col0 + wc + n * 16 + cl;
            int which = j >> 10;
            int c = j & 1023;
            int h = c >> 6, d = c & 63;
            float bv = bias[j];
#pragma unroll
            for (int r = 0; r < 4; ++r) {
                int i = i0 + r;
                int b = i >> 11, t = i & 2047;
                size_t bh = (size_t)(b * H_ + h);
                float val = acc[m][n][r] + bv;
                if (which == 0) {
                    Qo[(bh * T_ + t) * D_ + d] = f2bf(val * QSCALE);
                } else if (which == 1) {
                    Ko[(bh * T_ + t) * D_ + d] = f2bf(val);
                } else {
                    Vt[(bh * D_ + d) * T_ + t] = f2bf(val);
                }
            }
        }
    }
}

// ---------------- GEMM2: out = AO @ Wt2^T + b (fp32 out) ----------------
__global__ __launch_bounds__(256)
void gemm_proj_kernel(const unsigned short* __restrict__ A,   // [4096][1024] bf16
                      const unsigned short* __restrict__ Bt,  // [1024][1024] bf16
                      const float* __restrict__ bias,         // [1024]
                      float* __restrict__ out)                // [4096][1024] f32
{
    GEMM_PROLOGUE(blockIdx.x, blockIdx.y)

#pragma unroll
    for (int m = 0; m < 4; ++m) {
        int i0 = row0 + wr + m * 16 + g * 4;
#pragma unroll
        for (int n = 0; n < 4; ++n) {
            int j = col0 + wc + n * 16 + cl;
            float bv = bias[j];
#pragma unroll
            for (int r = 0; r < 4; ++r)
                out[(size_t)(i0 + r) * C_ + j] = acc[m][n][r] + bv;
        }
    }
}

// ---------------- flash attention (causal, swapped QK^T, 4 blocks/CU) ----------------
// grid 1024 (1-D): xcd = lin&7 (round-robin dispatch), idx = lin>>3;
// bh = xcd + 8*(idx&3) -> 4 heads per XCD (2MB K/V, L2-resident);
// qt = 31-(idx>>2) -> longest q-tiles dispatch first, 1-step tiles drain last.
// LDS = 16K K + 16K V (dbuf) + 8K swizzled Plds = 40960 B -> exactly 4 blocks/CU.
// Swapped operands: lane owns q-row; softmax per-lane + 2 shfl_xor; exp2 domain.
__global__ __launch_bounds__(256)
void attn_kernel(const unsigned short* __restrict__ Q,   // [BH][T][D], pre-scaled
                 const unsigned short* __restrict__ Kb,  // [BH][T][D]
                 const unsigned short* __restrict__ Vh_, // [BH][D][T]
                 unsigned short* __restrict__ AO)        // [B][T][C] bf16
{
    __shared__ unsigned short Klds[2][64 * 64];   // 16 KB
    __shared__ unsigned short Vlds[2][64 * 64];   // 16 KB
    __shared__ unsigned short Plds[4][16 * 64];   // 8 KB, XOR-swizzled rows
    const int lin = blockIdx.x;                   // 0..1023
    const int idx = lin >> 3;                     // 0..127
    const int bh  = (lin & 7) + 8 * (idx & 3);    // 0..31, head pinned to one XCD
    const int qt  = 31 - (idx >> 2);              // long tiles first
    const int b = bh >> 4, h = bh & 15;
    const int tid = threadIdx.x;
    const int lane = tid & 63;
    const int wave = tid >> 6;
    const int g = lane >> 4, cl = lane & 15;

    const unsigned short* Qh = Q + (size_t)bh * T_ * D_;
    const unsigned short* Kh = Kb + (size_t)bh * T_ * D_;
    const unsigned short* Vh = Vh_ + (size_t)bh * D_ * T_;

    const int srow = tid >> 3;  // 0..31
    const int sg   = tid & 7;
    const int pswz = (cl & 7) << 4;   // Plds byte-XOR (same involution write & read)

    // stage one 64x64 K tile + one 64x64 V^T tile; granule pre-swizzled lg = sg ^ (r&7)
    auto stage = [&](int bufi, int kb) {
#pragma unroll
        for (int c = 0; c < 2; ++c) {
            int r = srow + c * 32;
            int lg = sg ^ (r & 7);
            gld16(Kh + (size_t)(kb + r) * D_ + lg * 8,
                  (char*)&Klds[bufi][0] + c * 4096 + wave * 1024);
            gld16(Vh + (size_t)r * T_ + kb + lg * 8,
                  (char*)&Vlds[bufi][0] + c * 4096 + wave * 1024);
        }
    };

    const int q0 = qt * 64 + wave * 16;
    const int tq = q0 + cl;   // this lane's q row

    bf16x8 qf[2];
#pragma unroll
    for (int c2 = 0; c2 < 2; ++c2)
        qf[c2] = bload(Qh + (size_t)(q0 + cl) * D_ + c2 * 32 + g * 8);

    f32x4 oacc[4];
#pragma unroll
    for (int n = 0; n < 4; ++n) oacc[n] = (f32x4){0.f, 0.f, 0.f, 0.f};
    float m_run = -INFINITY, l_run = 0.f;

    const int nk = qt + 1;
    stage(0, 0);
    int buf = 0;
    for (int kt = 0; kt < nk; ++kt) {
        if (kt + 1 < nk) { stage(buf ^ 1, (kt + 1) * 64); VMCNT(4); }
        else             { VMCNT(0); }
        __builtin_amdgcn_s_barrier();

        const int kb = kt * 64;
        // ---- QK^T (swapped): sc[n] row = k, col = q ----
        f32x4 sc[4];
        __builtin_amdgcn_s_setprio(1);
#pragma unroll
        for (int n = 0; n < 4; ++n) {
            sc[n] = (f32x4){0.f, 0.f, 0.f, 0.f};
#pragma unroll
            for (int c2 = 0; c2 < 2; ++c2) {
                int pg = (c2 * 4 + g) ^ (cl & 7);
                bf16x8 kf = bload(&Klds[buf][(n * 16 + cl) * 64 + pg * 8]);
                sc[n] = __builtin_amdgcn_mfma_f32_16x16x32_bf16(kf, qf[c2], sc[n], 0, 0, 0);
            }
        }
        __builtin_amdgcn_s_setprio(0);
        // ---- causal mask (diagonal tile only); k = kb + n*16 + g*4 + r ----
        if (kt == qt) {
#pragma unroll
            for (int n = 0; n < 4; ++n) {
                int k4 = kb + n * 16 + g * 4;
#pragma unroll
                for (int r = 0; r < 4; ++r)
                    if (k4 + r > tq) sc[n][r] = -INFINITY;
            }
        }
        // ---- online softmax: per-lane 16 values + 2 shfl_xor across g ----
        float vmax = sc[0][0];
#pragma unroll
        for (int n = 0; n < 4; ++n)
#pragma unroll
            for (int r = 0; r < 4; ++r) vmax = fmaxf(vmax, sc[n][r]);
        vmax = fmaxf(vmax, __shfl_xor(vmax, 16, 64));
        vmax = fmaxf(vmax, __shfl_xor(vmax, 32, 64));
        float mn = fmaxf(m_run, vmax);
        float alpha = fexp2(m_run - mn);
        float p[4][4];
        float ps = 0.f;
#pragma unroll
        for (int n = 0; n < 4; ++n)
#pragma unroll
            for (int r = 0; r < 4; ++r) { p[n][r] = fexp2(sc[n][r] - mn); ps += p[n][r]; }
        ps += __shfl_xor(ps, 16, 64);
        ps += __shfl_xor(ps, 32, 64);
        l_run = l_run * alpha + ps;
        m_run = mn;
#pragma unroll
        for (int n = 0; n < 4; ++n)
#pragma unroll
            for (int r = 0; r < 4; ++r) oacc[n][r] *= alpha;
        // ---- P: pack bf16 pairs, 4x ds_write_b64 into own (swizzled) q-row ----
#pragma unroll
        for (int n = 0; n < 4; ++n) {
            uint2_t w;
            w.x = packbf(p[n][0], p[n][1]);
            w.y = packbf(p[n][2], p[n][3]);
            *(uint2_t*)((char*)&Plds[wave][0] + ((cl * 128 + n * 32 + g * 8) ^ pswz)) = w;
        }
        bf16x8 pf[2];
#pragma unroll
        for (int kk = 0; kk < 2; ++kk)
            pf[kk] = bload((const unsigned short*)
                ((char*)&Plds[wave][0] + ((cl * 128 + kk * 64 + g * 16) ^ pswz)));
        // ---- PV (swapped): O^T += mfma(V^T-frag, P^T-frag) ----
        __builtin_amdgcn_s_setprio(1);
#pragma unroll
        for (int n = 0; n < 4; ++n) {
#pragma unroll
            for (int kk = 0; kk < 2; ++kk) {
                int pg = (kk * 4 + g) ^ (cl & 7);
                bf16x8 vfr = bload(&Vlds[buf][(n * 16 + cl) * 64 + pg * 8]);
                oacc[n] = __builtin_amdgcn_mfma_f32_16x16x32_bf16(vfr, pf[kk], oacc[n], 0, 0, 0);
            }
        }
        __builtin_amdgcn_s_setprio(0);
        LGKM0;
        __builtin_amdgcn_s_barrier();
        buf ^= 1;
    }
    // ---- epilogue: lane owns row t = q0+cl; d = n*16 + g*4 + r ----
    float inv = 1.f / l_run;
#pragma unroll
    for (int n = 0; n < 4; ++n) {
        uint2_t w;
        w.x = packbf(oacc[n][0] * inv, oacc[n][1] * inv);
        w.y = packbf(oacc[n][2] * inv, oacc[n][3] * inv);
        *(uint2_t*)&AO[((size_t)b * T_ + tq) * C_ + h * D_ + n * 16 + g * 4] = w;
    }
}

extern "C" void kernel_launch(void* const* d_in, const int* in_sizes, int n_in,
                              void* d_out, int out_size, void* d_ws, size_t ws_size,
                              hipStream_t stream) {
    (void)in_sizes; (void)n_in; (void)out_size; (void)ws_size;
    const float* x      = (const float*)d_in[0];
    const float* w_attn = (const float*)d_in[1];
    const float* b_attn = (const float*)d_in[2];
    const float* w_proj = (const float*)d_in[3];
    const float* b_proj = (const float*)d_in[4];
    float* out = (float*)d_out;

    char* ws = (char*)d_ws;
    unsigned short* Xb  = (unsigned short*)(ws);
    unsigned short* Wt1 = (unsigned short*)(ws + ((size_t)8  << 20));
    unsigned short* Wt2 = (unsigned short*)(ws + ((size_t)14 << 20));
    unsigned short* Qb  = (unsigned short*)(ws + ((size_t)16 << 20));
    unsigned short* Kb  = (unsigned short*)(ws + ((size_t)24 << 20));
    unsigned short* Vt  = (unsigned short*)(ws + ((size_t)32 << 20));
    unsigned short* AO  = Xb;  // Xb dead after gemm_qkv

    cast_x_kernel<<<1024, 256, 0, stream>>>(x, Xb, (M1 * K_) / 4);
    transpose_cast_kernel<<<dim3(N1 / 32, K_ / 32), 256, 0, stream>>>(w_attn, Wt1, K_, N1);
    transpose_cast_kernel<<<dim3(C_ / 32, K_ / 32), 256, 0, stream>>>(w_proj, Wt2, K_, C_);
    gemm_qkv_kernel<<<dim3(M1 / 128, N1 / 128), 256, 0, stream>>>(Xb, Wt1, b_attn, Qb, Kb, Vt);
    attn_kernel<<<1024, 256, 0, stream>>>(Qb, Kb, Vt, AO);
    gemm_proj_kernel<<<dim3(M1 / 128, C_ / 128), 256, 0, stream>>>(AO, Wt2, b_proj, out);
}